// Round 3
// baseline (387.333 us; speedup 1.0000x reference)
//
#include <hip/hip_runtime.h>

// AttentionMatcher R10: 8 j-splits + launch_bounds(256,3).
// R9 post-mortem: occupancy stayed 21% because TOTAL regs (arch 104 +
// accum ~80 = ~184 unified) -> floor(512/184) = 2 waves/SIMD = 2 blocks/CU.
// R8 proved 4 blocks/CU resident when total<=128, but budget left only
// ~48 arch regs -> catastrophic spill. R10 targets the intermediate:
// bounds(256,3) -> total budget 170, compiler shaves ~14 arch regs
// (addressing remat, not MFMA operands) -> 3 blocks/CU, 1.5x overlap of
// the latency chain. Tripwire: FETCH_SIZE >> 41MB means it spilled.
// out = gate * softmax(N M^T, diag<-0) M + (1-gate) * N,  n=8192, d=256, fp32.
//
// ws: MhG [n][256] fp16 row-major          (QK B-plane)
//     MtG [n/32 tiles][256 d][32 j] fp16   (PV B-plane, transposed tile-major)
//     Ofp (nspl-1) fp16 partial O planes; split-0 partial f32 in d_out
//     MLm/MLl [nspl][n] f32 running max / sum per split.

constexpr int EMBED = 256;
constexpr int BQ = 64;
constexpr int BJ = 32;
constexpr int NT = 256;
constexpr int MAXSPL = 8;

constexpr int SS_OFF = 0;            // 2 planes x (64 x 36) f32 = 18432 B
constexpr int PH_OFF = 18432;        // 64 x 80 B (32 fp16 + pad)
constexpr int MS_OFF = 23552;
constexpr int LS_OFF = 23808;
constexpr int AS_OFF = 24064;
constexpr int LDS_SZ = 24320;        // x3 blocks/CU = 73 KB

typedef _Float16 half8 __attribute__((ext_vector_type(8)));
typedef float f32x4 __attribute__((ext_vector_type(4)));
typedef short short8v __attribute__((ext_vector_type(8)));

static __device__ __forceinline__ f32x4 mfma16(half8 a, half8 b, f32x4 c) {
    return __builtin_amdgcn_mfma_f32_16x16x32_f16(a, b, c, 0, 0, 0);
}
static __device__ __forceinline__ short f2h(float x) {
    return (short)__builtin_bit_cast(unsigned short, (_Float16)x);
}

// ---------- prep: fp16 row plane + fp16 transposed tile plane ----------
__global__ void prep(const float* __restrict__ M,
                     short* __restrict__ MhG, short* __restrict__ MtG) {
    __shared__ float L[16 * 260];
    const int r0 = blockIdx.x * 16;            // 16 M-rows per block
    const int t = threadIdx.x;
    const int pj = t >> 4, pc = (t & 15) * 16;
    {
        const float* src = M + (size_t)(r0 + pj) * EMBED + pc;
        float4 v[4];
        #pragma unroll
        for (int i = 0; i < 4; ++i) v[i] = ((const float4*)src)[i];
        short* hd = MhG + (size_t)(r0 + pj) * EMBED + pc;
        #pragma unroll
        for (int i = 0; i < 2; ++i) {
            float4 a = v[2 * i], b = v[2 * i + 1];
            short8v h;
            h[0]=f2h(a.x); h[1]=f2h(a.y); h[2]=f2h(a.z); h[3]=f2h(a.w);
            h[4]=f2h(b.x); h[5]=f2h(b.y); h[6]=f2h(b.z); h[7]=f2h(b.w);
            *(short8v*)(hd + 8 * i) = h;
        }
        #pragma unroll
        for (int i = 0; i < 4; ++i)
            *(float4*)(L + pj * 260 + pc + 4 * i) = v[i];
    }
    __syncthreads();
    {
        const int d = t;                        // 0..255
        const int tile = r0 >> 5, jh = (r0 >> 4) & 1;
        short* dst = MtG + (size_t)tile * (BJ * EMBED) + d * BJ + jh * 16;
        #pragma unroll
        for (int g2 = 0; g2 < 2; ++g2) {
            short8v w;
            #pragma unroll
            for (int e = 0; e < 8; ++e) w[e] = f2h(L[(g2 * 8 + e) * 260 + d]);
            *(short8v*)(dst + g2 * 8) = w;
        }
    }
}

// ---------- main split-j flash kernel (direct-from-L2 B-operands) ----------
__launch_bounds__(NT, 3)
__global__ void attn(const short* __restrict__ MhG, const short* __restrict__ MtG,
                     const float* __restrict__ Ng, const int* __restrict__ iseval_p,
                     float* __restrict__ O0out, short* __restrict__ Ofp,
                     float* __restrict__ MLm, float* __restrict__ MLl,
                     int n, int nspl, int jlen)
{
    __shared__ __align__(16) char smem[LDS_SZ];
    float* MS = (float*)(smem + MS_OFF);
    float* LS = (float*)(smem + LS_OFF);
    float* AS = (float*)(smem + AS_OFF);

    const int t = threadIdx.x, lane = t & 63, wave = t >> 6;
    const int quad = lane >> 4, mn = lane & 15;
    // XCD swizzle: bid%8 -> XCD. nspl=8: each XCD owns one split entirely.
    const int bid = blockIdx.x;
    int s, qb;
    if (nspl == 8) { s = bid & 7;        qb = bid >> 3; }
    else           { s = (bid & 7) >> 1; qb = ((bid >> 3) << 1) | (bid & 1); }
    const int q0 = qb * BQ;
    const int jbase = s * jlen;
    const int jb32 = jbase / BJ;
    const int ntiles = jlen / BJ;
    const int iseval = *iseval_p;
    const int jt = wave & 1, kh = wave >> 1;     // QK roles
    const int dq = wave;                         // PV d-quarter
    const int sq = t >> 2, sh = t & 3;           // softmax roles

    if (t < BQ) { MS[t] = -1e30f; LS[t] = 0.f; }

    // ---- Q fragments fp16 (A-layout): this wave's K-half only ----
    half8 Qf[4][4];
    #pragma unroll
    for (int qi = 0; qi < 4; ++qi) {
        const float* np = Ng + (size_t)(q0 + qi * 16 + mn) * EMBED;
        #pragma unroll
        for (int kk = 0; kk < 4; ++kk) {
            const float* p = np + (kh * 4 + kk) * 32 + quad * 8;
            float4 a = *(const float4*)p, b = *(const float4*)(p + 4);
            half8 h;
            h[0]=(_Float16)a.x; h[1]=(_Float16)a.y; h[2]=(_Float16)a.z; h[3]=(_Float16)a.w;
            h[4]=(_Float16)b.x; h[5]=(_Float16)b.y; h[6]=(_Float16)b.z; h[7]=(_Float16)b.w;
            Qf[qi][kk] = h;
        }
    }

    f32x4 O[4][4];
    #pragma unroll
    for (int qi = 0; qi < 4; ++qi)
        #pragma unroll
        for (int dt = 0; dt < 4; ++dt) O[qi][dt] = (f32x4){0.f, 0.f, 0.f, 0.f};

    // QK B base: row j = jbase + tile*BJ + jt*16 + mn, cols kh*128 + kk*32 + quad*8
    const short* mhb0 = MhG + (size_t)(jbase + jt * 16 + mn) * EMBED + kh * 128 + quad * 8;
    half8 Bc[4], Bn[4], Mtf[4];
    #pragma unroll
    for (int kk = 0; kk < 4; ++kk) Bc[kk] = *(const half8*)(mhb0 + kk * 32);

    __syncthreads();

    for (int tile = 0; tile < ntiles; ++tile) {
        const int j0g = jbase + tile * BJ;

        // --- QK^T: 4 q-tiles x this wave's (jt, K-half) -> SS plane kh ---
        {
            f32x4 a0 = (f32x4){0,0,0,0}, a1 = (f32x4){0,0,0,0};
            f32x4 a2 = (f32x4){0,0,0,0}, a3 = (f32x4){0,0,0,0};
            #pragma unroll
            for (int kk = 0; kk < 4; ++kk) {
                half8 bf = Bc[kk];
                a0 = mfma16(Qf[0][kk], bf, a0);
                a1 = mfma16(Qf[1][kk], bf, a1);
                a2 = mfma16(Qf[2][kk], bf, a2);
                a3 = mfma16(Qf[3][kk], bf, a3);
            }
            float* ssp = (float*)(smem + SS_OFF) + kh * 2304;
            #pragma unroll
            for (int r = 0; r < 4; ++r) {
                ssp[(0  + quad * 4 + r) * 36 + jt * 16 + mn] = a0[r];
                ssp[(16 + quad * 4 + r) * 36 + jt * 16 + mn] = a1[r];
                ssp[(32 + quad * 4 + r) * 36 + jt * 16 + mn] = a2[r];
                ssp[(48 + quad * 4 + r) * 36 + jt * 16 + mn] = a3[r];
            }
        }
        __syncthreads();   // b1: SS visible

        // --- register prefetch (latency covered by softmax): ---
        if (tile + 1 < ntiles) {
            const short* nb = mhb0 + (size_t)(tile + 1) * (BJ * EMBED);
            #pragma unroll
            for (int kk = 0; kk < 4; ++kk) Bn[kk] = *(const half8*)(nb + kk * 32);
        }
        {
            const short* mtb = MtG + (size_t)(jb32 + tile) * (BJ * EMBED);
            #pragma unroll
            for (int dt = 0; dt < 4; ++dt)
                Mtf[dt] = *(const half8*)(mtb + (dq * 64 + dt * 16 + mn) * BJ + quad * 8);
        }

        // --- online softmax: thread (sq, sh) owns j = 8sh..8sh+7 ---
        {
            const float* p0 = (const float*)(smem + SS_OFF) + sq * 36 + 8 * sh;
            float4 sa = *(const float4*)p0;
            float4 sb = *(const float4*)(p0 + 4);
            float4 sc = *(const float4*)(p0 + 2304);
            float4 sd = *(const float4*)(p0 + 2308);
            float sv[8] = {sa.x + sc.x, sa.y + sc.y, sa.z + sc.z, sa.w + sc.w,
                           sb.x + sd.x, sb.y + sd.y, sb.z + sd.z, sb.w + sd.w};
            const int qg = q0 + sq;
            if (iseval) {
                if (qg == 0) {
                    #pragma unroll
                    for (int i = 0; i < 8; ++i) sv[i] = 0.f;
                }
            } else {
                int dj = qg - j0g - 8 * sh;
                #pragma unroll
                for (int i = 0; i < 8; ++i) if (dj == i) sv[i] = 0.f;
            }
            float mx = sv[0];
            #pragma unroll
            for (int i = 1; i < 8; ++i) mx = fmaxf(mx, sv[i]);
            mx = fmaxf(mx, __shfl_xor(mx, 1));
            mx = fmaxf(mx, __shfl_xor(mx, 2));
            float m_old = MS[sq];
            float m_new = fmaxf(m_old, mx);
            float alpha = __expf(m_old - m_new);
            float p[8], ps = 0.f;
            #pragma unroll
            for (int i = 0; i < 8; ++i) { p[i] = __expf(sv[i] - m_new); ps += p[i]; }
            ps += __shfl_xor(ps, 1);
            ps += __shfl_xor(ps, 2);
            if (sh == 0) {
                MS[sq] = m_new;
                AS[sq] = alpha;
                LS[sq] = LS[sq] * alpha + ps;
            }
            half8 ph;
            #pragma unroll
            for (int i = 0; i < 8; ++i) ph[i] = (_Float16)p[i];
            *(half8*)(smem + PH_OFF + sq * 80 + sh * 16) = ph;
        }
        __syncthreads();   // b2: PH/AS visible

        // --- PV: 4 q-tiles x this wave's 4 d-tiles, K=32 ---
        #pragma unroll
        for (int qi = 0; qi < 4; ++qi) {
            half8 pf = *(const half8*)(smem + PH_OFF + (qi * 16 + mn) * 80 + quad * 16);
            f32x4 al = *(const f32x4*)((const float*)(smem + AS_OFF) + qi * 16 + quad * 4);
            #pragma unroll
            for (int dt = 0; dt < 4; ++dt) {
                f32x4 o = O[qi][dt];
                o[0] *= al[0]; o[1] *= al[1]; o[2] *= al[2]; o[3] *= al[3];
                O[qi][dt] = mfma16(pf, Mtf[dt], o);
            }
        }
        #pragma unroll
        for (int kk = 0; kk < 4; ++kk) Bc[kk] = Bn[kk];
        // SS rewrite (QK t+1) safe: softmax(t) finished reading before b2.
        // PH/AS rewrite (softmax t+1) fenced by b1(t+1), after PV(t).
    }

    // ---- epilogue: partial O + (m,l) per split ----
    if (s == 0) {
        #pragma unroll
        for (int qi = 0; qi < 4; ++qi)
            #pragma unroll
            for (int dt = 0; dt < 4; ++dt) {
                int col = dq * 64 + dt * 16 + mn;
                #pragma unroll
                for (int r = 0; r < 4; ++r)
                    O0out[(size_t)(q0 + qi * 16 + quad * 4 + r) * EMBED + col] = O[qi][dt][r];
            }
    } else {
        short* dst = Ofp + (size_t)(s - 1) * n * EMBED;
        #pragma unroll
        for (int qi = 0; qi < 4; ++qi)
            #pragma unroll
            for (int dt = 0; dt < 4; ++dt) {
                int col = dq * 64 + dt * 16 + mn;
                #pragma unroll
                for (int r = 0; r < 4; ++r)
                    dst[(size_t)(q0 + qi * 16 + quad * 4 + r) * EMBED + col] = f2h(O[qi][dt][r]);
            }
    }
    if (t < BQ) {
        MLm[s * n + q0 + t] = MS[t];
        MLl[s * n + q0 + t] = LS[t];
    }
}

// ---------- combine nspl partials + gate + blend ----------
__global__ void combineK(const float* __restrict__ O0, const short* __restrict__ Ofp,
                         const float* __restrict__ MLm, const float* __restrict__ MLl,
                         const float* __restrict__ Ng, const float* __restrict__ Wg,
                         const float* __restrict__ bg, const float* __restrict__ gb,
                         float* __restrict__ out, int n, int nspl)
{
    const int t = threadIdx.x;
    const int row = blockIdx.x * 16 + (t >> 4);
    const int c = t & 15;
    float ms[MAXSPL], ls[MAXSPL];
    for (int k = 0; k < nspl; ++k) { ms[k] = MLm[k * n + row]; ls[k] = MLl[k * n + row]; }
    float m = ms[0];
    for (int k = 1; k < nspl; ++k) m = fmaxf(m, ms[k]);
    float w[MAXSPL], lsum = 0.f;
    for (int k = 0; k < nspl; ++k) { w[k] = __expf(ms[k] - m); lsum += w[k] * ls[k]; }
    float linv = 1.f / lsum;

    float acc[16];
    {
        const float4* o0 = (const float4*)(O0 + (size_t)row * EMBED + c * 16);
        #pragma unroll
        for (int i = 0; i < 4; ++i) {
            float4 v = o0[i];
            acc[4*i+0] = w[0] * v.x; acc[4*i+1] = w[0] * v.y;
            acc[4*i+2] = w[0] * v.z; acc[4*i+3] = w[0] * v.w;
        }
    }
    for (int k = 1; k < nspl; ++k) {
        const short* op = Ofp + (size_t)(k - 1) * n * EMBED + (size_t)row * EMBED + c * 16;
        half8 a = *(const half8*)op, b = *(const half8*)(op + 8);
        #pragma unroll
        for (int i = 0; i < 8; ++i) {
            acc[i]     += w[k] * (float)a[i];
            acc[8 + i] += w[k] * (float)b[i];
        }
    }
    float dot = 0.f;
    #pragma unroll
    for (int i = 0; i < 16; ++i) { acc[i] *= linv; dot += acc[i] * Wg[c * 16 + i]; }
    dot += __shfl_xor(dot, 1);
    dot += __shfl_xor(dot, 2);
    dot += __shfl_xor(dot, 4);
    dot += __shfl_xor(dot, 8);
    float g = 1.f / (1.f + __expf(-(dot + bg[0] + gb[0])));
    const float4* n4 = (const float4*)(Ng + (size_t)row * EMBED + c * 16);
    float4* o4 = (float4*)(out + (size_t)row * EMBED + c * 16);
    #pragma unroll
    for (int i = 0; i < 4; ++i) {
        float4 nn = n4[i];
        float4 res;
        res.x = acc[4*i+0] * g + nn.x * (1.f - g);
        res.y = acc[4*i+1] * g + nn.y * (1.f - g);
        res.z = acc[4*i+2] * g + nn.z * (1.f - g);
        res.w = acc[4*i+3] * g + nn.w * (1.f - g);
        o4[i] = res;
    }
}

extern "C" void kernel_launch(void* const* d_in, const int* in_sizes, int n_in,
                              void* d_out, int out_size, void* d_ws, size_t ws_size,
                              hipStream_t stream) {
    const float* M      = (const float*)d_in[0];
    const float* N      = (const float*)d_in[1];
    const float* Wgp    = (const float*)d_in[2];
    const float* bgp    = (const float*)d_in[3];
    const float* gbp    = (const float*)d_in[4];
    const int*   iseval = (const int*)d_in[5];
    float* out = (float*)d_out;

    int n = in_sizes[0] / EMBED;   // 8192

    int nspl = 8;
    // ws: MhG + MtG (2 fp16 planes) + (nspl-1) fp16 O planes + 2*nspl*n f32
    size_t need8 = (size_t)2 * n * EMBED * 2 + (size_t)(8 - 1) * n * EMBED * 2
                 + (size_t)2 * 8 * n * 4;
    if (ws_size && ws_size < need8) nspl = 4;   // fallback: previous layout fits 20.3MB

    short* MhG = (short*)d_ws;                          // n*256 fp16 = 4 MB
    short* MtG = MhG + (size_t)n * EMBED;               // n*256 fp16 = 4 MB
    short* Ofp = MtG + (size_t)n * EMBED;               // (nspl-1)*n*256 fp16
    float* MLm = (float*)(Ofp + (size_t)(nspl - 1) * n * EMBED);
    float* MLl = MLm + (size_t)nspl * n;

    int jlen = n / nspl;
    hipLaunchKernelGGL(prep, dim3(n / 16), dim3(NT), 0, stream, M, MhG, MtG);
    hipLaunchKernelGGL(attn, dim3((n / BQ) * nspl), dim3(NT), 0, stream,
                       MhG, MtG, N, iseval, out, Ofp, MLm, MLl, n, nspl, jlen);
    hipLaunchKernelGGL(combineK, dim3(n / 16), dim3(NT), 0, stream,
                       out, Ofp, MLm, MLl, N, Wgp, bgp, gbp, out, n, nspl);
}

// Round 4
// 283.523 us; speedup vs baseline: 1.3661x; 1.3661x over previous
//
#include <hip/hip_runtime.h>

// AttentionMatcher R11: 8-wave blocks (NT=512), 2 q-tiles/wave.
// R8/R9/R10 post-mortem: per-wave state (Qf[4][4]=64 + O[4][4]=64 accum
// + ~56 misc = ~184 unified regs) structurally caps 2 waves/SIMD; any
// launch_bounds squeeze just spills (R8 FETCH 1.2GB, R10 68MB+72MB WRITE).
// R11 halves per-wave state instead: BQ=64 split across 8 waves (2 q-tiles
// each) -> ~112 regs/wave -> 4 waves/SIMD fits under bounds(512,4) with
// ~16 regs headroom (no spill expected). Grid 512 blocks (nspl=4, R7's
// proven split) -> 2 blocks/CU x 8 waves = 16 waves/CU: 2x the overlap of
// the per-tile barrier+softmax+L2 latency chain vs R7's 117us.
// Tripwire: FETCH_SIZE >= 150MB means the 128-reg budget spilled -> revert.
// out = gate * softmax(N M^T, diag<-0) M + (1-gate) * N,  n=8192, d=256, fp32.
//
// ws: MhG [n][256] fp16 row-major          (QK B-plane)
//     MtG [n/32 tiles][256 d][32 j] fp16   (PV B-plane, transposed tile-major)
//     Ofp 3 fp16 partial O planes; split-0 partial f32 in d_out
//     MLm/MLl [4][n] f32 running max / sum per split.

constexpr int EMBED = 256;
constexpr int BQ = 64;
constexpr int BJ = 32;
constexpr int NT = 256;    // prep / combine block size
constexpr int NTA = 512;   // attn block size (8 waves)
constexpr int MAXSPL = 8;

constexpr int SS_OFF = 0;            // 2 planes x (64 x 36) f32 = 18432 B
constexpr int PH_OFF = 18432;        // 64 x 80 B (32 fp16 + pad)
constexpr int MS_OFF = 23552;
constexpr int LS_OFF = 23808;
constexpr int AS_OFF = 24064;
constexpr int LDS_SZ = 24320;        // x2 blocks/CU = 48.6 KB

typedef _Float16 half8 __attribute__((ext_vector_type(8)));
typedef _Float16 half4v __attribute__((ext_vector_type(4)));
typedef float f32x4 __attribute__((ext_vector_type(4)));
typedef short short8v __attribute__((ext_vector_type(8)));

static __device__ __forceinline__ f32x4 mfma16(half8 a, half8 b, f32x4 c) {
    return __builtin_amdgcn_mfma_f32_16x16x32_f16(a, b, c, 0, 0, 0);
}
static __device__ __forceinline__ short f2h(float x) {
    return (short)__builtin_bit_cast(unsigned short, (_Float16)x);
}

// ---------- prep: fp16 row plane + fp16 transposed tile plane ----------
__global__ void prep(const float* __restrict__ M,
                     short* __restrict__ MhG, short* __restrict__ MtG) {
    __shared__ float L[16 * 260];
    const int r0 = blockIdx.x * 16;            // 16 M-rows per block
    const int t = threadIdx.x;
    const int pj = t >> 4, pc = (t & 15) * 16;
    {
        const float* src = M + (size_t)(r0 + pj) * EMBED + pc;
        float4 v[4];
        #pragma unroll
        for (int i = 0; i < 4; ++i) v[i] = ((const float4*)src)[i];
        short* hd = MhG + (size_t)(r0 + pj) * EMBED + pc;
        #pragma unroll
        for (int i = 0; i < 2; ++i) {
            float4 a = v[2 * i], b = v[2 * i + 1];
            short8v h;
            h[0]=f2h(a.x); h[1]=f2h(a.y); h[2]=f2h(a.z); h[3]=f2h(a.w);
            h[4]=f2h(b.x); h[5]=f2h(b.y); h[6]=f2h(b.z); h[7]=f2h(b.w);
            *(short8v*)(hd + 8 * i) = h;
        }
        #pragma unroll
        for (int i = 0; i < 4; ++i)
            *(float4*)(L + pj * 260 + pc + 4 * i) = v[i];
    }
    __syncthreads();
    {
        const int d = t;                        // 0..255
        const int tile = r0 >> 5, jh = (r0 >> 4) & 1;
        short* dst = MtG + (size_t)tile * (BJ * EMBED) + d * BJ + jh * 16;
        #pragma unroll
        for (int g2 = 0; g2 < 2; ++g2) {
            short8v w;
            #pragma unroll
            for (int e = 0; e < 8; ++e) w[e] = f2h(L[(g2 * 8 + e) * 260 + d]);
            *(short8v*)(dst + g2 * 8) = w;
        }
    }
}

// ---------- main split-j flash kernel (8 waves, 2 q-tiles/wave) ----------
__launch_bounds__(NTA, 4)
__global__ void attn(const short* __restrict__ MhG, const short* __restrict__ MtG,
                     const float* __restrict__ Ng, const int* __restrict__ iseval_p,
                     float* __restrict__ O0out, short* __restrict__ Ofp,
                     float* __restrict__ MLm, float* __restrict__ MLl,
                     int n, int nspl, int jlen)
{
    __shared__ __align__(16) char smem[LDS_SZ];
    float* MS = (float*)(smem + MS_OFF);
    float* LS = (float*)(smem + LS_OFF);
    float* AS = (float*)(smem + AS_OFF);

    const int t = threadIdx.x, lane = t & 63, wave = t >> 6;   // wave 0..7
    const int quad = lane >> 4, mn = lane & 15;
    // XCD swizzle (R7 mapping): bid%8 -> XCD; 2 XCDs per split, qb interleave.
    const int bid = blockIdx.x;
    const int s  = (bid & 7) >> 1;               // split 0..3
    const int qb = ((bid >> 3) << 1) | (bid & 1);// 0..127
    const int q0 = qb * BQ;
    const int jbase = s * jlen;
    const int jb32 = jbase / BJ;
    const int ntiles = jlen / BJ;                // 64
    const int iseval = *iseval_p;
    const int jt = wave & 1, kh = (wave >> 1) & 1, qh = wave >> 2;  // QK roles
    const int dq = wave & 3;                     // PV d-quarter (qh = q-half)
    const int sq = t >> 3, sh = t & 7;           // softmax: 64 rows x 8 thr

    if (t < BQ) { MS[t] = -1e30f; LS[t] = 0.f; }

    // ---- Q fragments fp16 (A-layout): this wave's q-half + K-half ----
    half8 Qf[2][4];
    #pragma unroll
    for (int qi = 0; qi < 2; ++qi) {
        const float* np = Ng + (size_t)(q0 + (qh * 2 + qi) * 16 + mn) * EMBED;
        #pragma unroll
        for (int kk = 0; kk < 4; ++kk) {
            const float* p = np + (kh * 4 + kk) * 32 + quad * 8;
            float4 a = *(const float4*)p, b = *(const float4*)(p + 4);
            half8 h;
            h[0]=(_Float16)a.x; h[1]=(_Float16)a.y; h[2]=(_Float16)a.z; h[3]=(_Float16)a.w;
            h[4]=(_Float16)b.x; h[5]=(_Float16)b.y; h[6]=(_Float16)b.z; h[7]=(_Float16)b.w;
            Qf[qi][kk] = h;
        }
    }

    f32x4 O[2][4];
    #pragma unroll
    for (int qi = 0; qi < 2; ++qi)
        #pragma unroll
        for (int dt = 0; dt < 4; ++dt) O[qi][dt] = (f32x4){0.f, 0.f, 0.f, 0.f};

    // QK B base: row j = jbase + tile*BJ + jt*16 + mn, cols kh*128 + kk*32 + quad*8
    const short* mhb0 = MhG + (size_t)(jbase + jt * 16 + mn) * EMBED + kh * 128 + quad * 8;
    half8 Bc[4], Bn[4], Mtf[4];
    #pragma unroll
    for (int kk = 0; kk < 4; ++kk) Bc[kk] = *(const half8*)(mhb0 + kk * 32);

    __syncthreads();

    for (int tile = 0; tile < ntiles; ++tile) {
        const int j0g = jbase + tile * BJ;

        // --- QK^T: this wave's 2 q-tiles x (jt, K-half) -> SS plane kh ---
        {
            f32x4 a0 = (f32x4){0,0,0,0}, a1 = (f32x4){0,0,0,0};
            #pragma unroll
            for (int kk = 0; kk < 4; ++kk) {
                half8 bf = Bc[kk];
                a0 = mfma16(Qf[0][kk], bf, a0);
                a1 = mfma16(Qf[1][kk], bf, a1);
            }
            float* ssp = (float*)(smem + SS_OFF) + kh * 2304;
            const int rb = qh * 32;
            #pragma unroll
            for (int r = 0; r < 4; ++r) {
                ssp[(rb +      quad * 4 + r) * 36 + jt * 16 + mn] = a0[r];
                ssp[(rb + 16 + quad * 4 + r) * 36 + jt * 16 + mn] = a1[r];
            }
        }
        __syncthreads();   // b1: SS visible

        // --- register prefetch (latency covered by softmax): ---
        if (tile + 1 < ntiles) {
            const short* nb = mhb0 + (size_t)(tile + 1) * (BJ * EMBED);
            #pragma unroll
            for (int kk = 0; kk < 4; ++kk) Bn[kk] = *(const half8*)(nb + kk * 32);
        }
        {
            const short* mtb = MtG + (size_t)(jb32 + tile) * (BJ * EMBED);
            #pragma unroll
            for (int dt = 0; dt < 4; ++dt)
                Mtf[dt] = *(const half8*)(mtb + (dq * 64 + dt * 16 + mn) * BJ + quad * 8);
        }

        // --- online softmax: thread (sq, sh) owns j = 4sh..4sh+3 ---
        {
            const float* p0 = (const float*)(smem + SS_OFF) + sq * 36 + 4 * sh;
            float4 sa = *(const float4*)p0;
            float4 sc = *(const float4*)(p0 + 2304);
            float sv[4] = {sa.x + sc.x, sa.y + sc.y, sa.z + sc.z, sa.w + sc.w};
            const int qg = q0 + sq;
            if (iseval) {
                if (qg == 0) {
                    #pragma unroll
                    for (int i = 0; i < 4; ++i) sv[i] = 0.f;
                }
            } else {
                int dj = qg - j0g - 4 * sh;
                #pragma unroll
                for (int i = 0; i < 4; ++i) if (dj == i) sv[i] = 0.f;
            }
            float mx = fmaxf(fmaxf(sv[0], sv[1]), fmaxf(sv[2], sv[3]));
            mx = fmaxf(mx, __shfl_xor(mx, 1));
            mx = fmaxf(mx, __shfl_xor(mx, 2));
            mx = fmaxf(mx, __shfl_xor(mx, 4));
            float m_old = MS[sq];
            float m_new = fmaxf(m_old, mx);
            float alpha = __expf(m_old - m_new);
            float p[4], ps = 0.f;
            #pragma unroll
            for (int i = 0; i < 4; ++i) { p[i] = __expf(sv[i] - m_new); ps += p[i]; }
            ps += __shfl_xor(ps, 1);
            ps += __shfl_xor(ps, 2);
            ps += __shfl_xor(ps, 4);
            if (sh == 0) {
                MS[sq] = m_new;
                AS[sq] = alpha;
                LS[sq] = LS[sq] * alpha + ps;
            }
            half4v ph;
            #pragma unroll
            for (int i = 0; i < 4; ++i) ph[i] = (_Float16)p[i];
            *(half4v*)(smem + PH_OFF + sq * 80 + sh * 8) = ph;
        }
        __syncthreads();   // b2: PH/AS visible

        // --- PV: this wave's 2 q-tiles x 4 d-tiles (quarter dq), K=32 ---
        #pragma unroll
        for (int qi = 0; qi < 2; ++qi) {
            const int qt = qh * 2 + qi;
            half8 pf = *(const half8*)(smem + PH_OFF + (qt * 16 + mn) * 80 + quad * 16);
            f32x4 al = *(const f32x4*)((const float*)(smem + AS_OFF) + qt * 16 + quad * 4);
            #pragma unroll
            for (int dt = 0; dt < 4; ++dt) {
                f32x4 o = O[qi][dt];
                o[0] *= al[0]; o[1] *= al[1]; o[2] *= al[2]; o[3] *= al[3];
                O[qi][dt] = mfma16(pf, Mtf[dt], o);
            }
        }
        #pragma unroll
        for (int kk = 0; kk < 4; ++kk) Bc[kk] = Bn[kk];
        // SS rewrite (QK t+1) safe: softmax(t) finished reading before b2.
        // PH/AS rewrite (softmax t+1) fenced by b1(t+1), after PV(t).
    }

    // ---- epilogue: partial O + (m,l) per split ----
    if (s == 0) {
        #pragma unroll
        for (int qi = 0; qi < 2; ++qi)
            #pragma unroll
            for (int dt = 0; dt < 4; ++dt) {
                int row = q0 + (qh * 2 + qi) * 16 + quad * 4;
                int col = dq * 64 + dt * 16 + mn;
                #pragma unroll
                for (int r = 0; r < 4; ++r)
                    O0out[(size_t)(row + r) * EMBED + col] = O[qi][dt][r];
            }
    } else {
        short* dst = Ofp + (size_t)(s - 1) * n * EMBED;
        #pragma unroll
        for (int qi = 0; qi < 2; ++qi)
            #pragma unroll
            for (int dt = 0; dt < 4; ++dt) {
                int row = q0 + (qh * 2 + qi) * 16 + quad * 4;
                int col = dq * 64 + dt * 16 + mn;
                #pragma unroll
                for (int r = 0; r < 4; ++r)
                    dst[(size_t)(row + r) * EMBED + col] = f2h(O[qi][dt][r]);
            }
    }
    if (t < BQ) {
        MLm[s * n + q0 + t] = MS[t];
        MLl[s * n + q0 + t] = LS[t];
    }
}

// ---------- combine nspl partials + gate + blend ----------
__global__ void combineK(const float* __restrict__ O0, const short* __restrict__ Ofp,
                         const float* __restrict__ MLm, const float* __restrict__ MLl,
                         const float* __restrict__ Ng, const float* __restrict__ Wg,
                         const float* __restrict__ bg, const float* __restrict__ gb,
                         float* __restrict__ out, int n, int nspl)
{
    const int t = threadIdx.x;
    const int row = blockIdx.x * 16 + (t >> 4);
    const int c = t & 15;
    float ms[MAXSPL], ls[MAXSPL];
    for (int k = 0; k < nspl; ++k) { ms[k] = MLm[k * n + row]; ls[k] = MLl[k * n + row]; }
    float m = ms[0];
    for (int k = 1; k < nspl; ++k) m = fmaxf(m, ms[k]);
    float w[MAXSPL], lsum = 0.f;
    for (int k = 0; k < nspl; ++k) { w[k] = __expf(ms[k] - m); lsum += w[k] * ls[k]; }
    float linv = 1.f / lsum;

    float acc[16];
    {
        const float4* o0 = (const float4*)(O0 + (size_t)row * EMBED + c * 16);
        #pragma unroll
        for (int i = 0; i < 4; ++i) {
            float4 v = o0[i];
            acc[4*i+0] = w[0] * v.x; acc[4*i+1] = w[0] * v.y;
            acc[4*i+2] = w[0] * v.z; acc[4*i+3] = w[0] * v.w;
        }
    }
    for (int k = 1; k < nspl; ++k) {
        const short* op = Ofp + (size_t)(k - 1) * n * EMBED + (size_t)row * EMBED + c * 16;
        half8 a = *(const half8*)op, b = *(const half8*)(op + 8);
        #pragma unroll
        for (int i = 0; i < 8; ++i) {
            acc[i]     += w[k] * (float)a[i];
            acc[8 + i] += w[k] * (float)b[i];
        }
    }
    float dot = 0.f;
    #pragma unroll
    for (int i = 0; i < 16; ++i) { acc[i] *= linv; dot += acc[i] * Wg[c * 16 + i]; }
    dot += __shfl_xor(dot, 1);
    dot += __shfl_xor(dot, 2);
    dot += __shfl_xor(dot, 4);
    dot += __shfl_xor(dot, 8);
    float g = 1.f / (1.f + __expf(-(dot + bg[0] + gb[0])));
    const float4* n4 = (const float4*)(Ng + (size_t)row * EMBED + c * 16);
    float4* o4 = (float4*)(out + (size_t)row * EMBED + c * 16);
    #pragma unroll
    for (int i = 0; i < 4; ++i) {
        float4 nn = n4[i];
        float4 res;
        res.x = acc[4*i+0] * g + nn.x * (1.f - g);
        res.y = acc[4*i+1] * g + nn.y * (1.f - g);
        res.z = acc[4*i+2] * g + nn.z * (1.f - g);
        res.w = acc[4*i+3] * g + nn.w * (1.f - g);
        o4[i] = res;
    }
}

extern "C" void kernel_launch(void* const* d_in, const int* in_sizes, int n_in,
                              void* d_out, int out_size, void* d_ws, size_t ws_size,
                              hipStream_t stream) {
    const float* M      = (const float*)d_in[0];
    const float* N      = (const float*)d_in[1];
    const float* Wgp    = (const float*)d_in[2];
    const float* bgp    = (const float*)d_in[3];
    const float* gbp    = (const float*)d_in[4];
    const int*   iseval = (const int*)d_in[5];
    float* out = (float*)d_out;

    int n = in_sizes[0] / EMBED;   // 8192
    const int nspl = 4;            // R7's proven split count (ws 20.3 MB)

    short* MhG = (short*)d_ws;                          // n*256 fp16 = 4 MB
    short* MtG = MhG + (size_t)n * EMBED;               // n*256 fp16 = 4 MB
    short* Ofp = MtG + (size_t)n * EMBED;               // 3*n*256 fp16 = 12 MB
    float* MLm = (float*)(Ofp + (size_t)(nspl - 1) * n * EMBED);
    float* MLl = MLm + (size_t)nspl * n;

    int jlen = n / nspl;
    hipLaunchKernelGGL(prep, dim3(n / 16), dim3(NT), 0, stream, M, MhG, MtG);
    hipLaunchKernelGGL(attn, dim3((n / BQ) * nspl), dim3(NTA), 0, stream,
                       MhG, MtG, N, iseval, out, Ofp, MLm, MLl, n, nspl, jlen);
    hipLaunchKernelGGL(combineK, dim3(n / 16), dim3(NT), 0, stream,
                       out, Ofp, MLm, MLl, N, Wgp, bgp, gbp, out, n, nspl);
}

// Round 5
// 185.283 us; speedup vs baseline: 2.0905x; 1.5302x over previous
//
#include <hip/hip_runtime.h>

// AttentionMatcher R12: single-barrier software pipeline (R7 base).
// R8-R11 post-mortem: occupancy lever is dead (R11: 2x waves/CU -> 24->13%
// MfmaUtil, 117->215us; barrier lockstep cost grows with waves/block).
// Bottleneck is the serial per-tile chain: QK -> b1 -> softmax -> b2 -> PV
// (~4400cyc vs ~600cyc issue work). R12 double-buffers SS/PH/AS and merges
// to ONE barrier/tile:
//   iter tt: [Mtf(tt-1) prefetch | QK(tt)->SS[tt&1] | Bn prefetch |
//             softmax(tt-1): SS[(tt-1)&1] -> PH/AS[(tt-1)&1]]
//            barrier
//            [PV(tt-1)]
// 65 barriers instead of 128; QK MFMA overlaps softmax VALU (separate
// pipes); Mtf L2 latency hidden behind QK+softmax.
// Hazards: SS[p] rewrite (QK tt) is post-barrier(tt-1) > softmax(tt-2) read;
// PH/AS[p] rewrite (softmax tt+1) separated from PV(tt-1) read by barrier(tt).
// out = gate * softmax(N M^T, diag<-0) M + (1-gate) * N,  n=8192, d=256, fp32.
//
// ws: MhG [n][256] fp16 row-major          (QK B-plane)
//     MtG [n/32 tiles][256 d][32 j] fp16   (PV B-plane, transposed tile-major)
//     Ofp 3 fp16 partial O planes (splits 1..3); split-0 partial f32 in d_out
//     MLm/MLl [4][n] f32 running max / sum per split.

constexpr int EMBED = 256;
constexpr int BQ = 64;
constexpr int BJ = 32;
constexpr int NT = 256;

constexpr int SS_OFF = 0;            // 2 buf x 2 planes x (64 x 36) f32
constexpr int SS_BUF = 18432;        // bytes per SS buffer (2 planes)
constexpr int PH_OFF = 36864;        // 2 buf x 64 x 80 B
constexpr int PH_BUF = 5120;
constexpr int MS_OFF = 47104;
constexpr int LS_OFF = 47360;
constexpr int AS_OFF = 47616;        // 2 buf x 256 B
constexpr int AS_BUF = 256;
constexpr int LDS_SZ = 48128;        // x2 blocks/CU = 96.3 KB (<160)

typedef _Float16 half8 __attribute__((ext_vector_type(8)));
typedef float f32x4 __attribute__((ext_vector_type(4)));
typedef short short8v __attribute__((ext_vector_type(8)));

static __device__ __forceinline__ f32x4 mfma16(half8 a, half8 b, f32x4 c) {
    return __builtin_amdgcn_mfma_f32_16x16x32_f16(a, b, c, 0, 0, 0);
}
static __device__ __forceinline__ short f2h(float x) {
    return (short)__builtin_bit_cast(unsigned short, (_Float16)x);
}

// ---------- prep: fp16 row plane + fp16 transposed tile plane ----------
__global__ void prep(const float* __restrict__ M,
                     short* __restrict__ MhG, short* __restrict__ MtG) {
    __shared__ float L[16 * 260];
    const int r0 = blockIdx.x * 16;            // 16 M-rows per block
    const int t = threadIdx.x;
    const int pj = t >> 4, pc = (t & 15) * 16;
    {
        const float* src = M + (size_t)(r0 + pj) * EMBED + pc;
        float4 v[4];
        #pragma unroll
        for (int i = 0; i < 4; ++i) v[i] = ((const float4*)src)[i];
        short* hd = MhG + (size_t)(r0 + pj) * EMBED + pc;
        #pragma unroll
        for (int i = 0; i < 2; ++i) {
            float4 a = v[2 * i], b = v[2 * i + 1];
            short8v h;
            h[0]=f2h(a.x); h[1]=f2h(a.y); h[2]=f2h(a.z); h[3]=f2h(a.w);
            h[4]=f2h(b.x); h[5]=f2h(b.y); h[6]=f2h(b.z); h[7]=f2h(b.w);
            *(short8v*)(hd + 8 * i) = h;
        }
        #pragma unroll
        for (int i = 0; i < 4; ++i)
            *(float4*)(L + pj * 260 + pc + 4 * i) = v[i];
    }
    __syncthreads();
    {
        const int d = t;                        // 0..255
        const int tile = r0 >> 5, jh = (r0 >> 4) & 1;
        short* dst = MtG + (size_t)tile * (BJ * EMBED) + d * BJ + jh * 16;
        #pragma unroll
        for (int g2 = 0; g2 < 2; ++g2) {
            short8v w;
            #pragma unroll
            for (int e = 0; e < 8; ++e) w[e] = f2h(L[(g2 * 8 + e) * 260 + d]);
            *(short8v*)(dst + g2 * 8) = w;
        }
    }
}

// ---------- main split-j flash kernel: 1-barrier pipelined ----------
__launch_bounds__(NT, 2)
__global__ void attn(const short* __restrict__ MhG, const short* __restrict__ MtG,
                     const float* __restrict__ Ng, const int* __restrict__ iseval_p,
                     float* __restrict__ O0out, short* __restrict__ Ofp,
                     float* __restrict__ MLm, float* __restrict__ MLl, int n)
{
    __shared__ __align__(16) char smem[LDS_SZ];
    float* MS = (float*)(smem + MS_OFF);
    float* LS = (float*)(smem + LS_OFF);

    const int t = threadIdx.x, lane = t & 63, wave = t >> 6;
    const int quad = lane >> 4, mn = lane & 15;
    // XCD swizzle: bid%8 -> XCD; all 64 blocks on an XCD share one split s.
    const int bid = blockIdx.x;
    const int s  = (bid & 7) >> 1;               // split 0..3
    const int qb = ((bid >> 3) << 1) | (bid & 1);// 0..127
    const int q0 = qb * BQ;
    const int jbase = s * (n >> 2);
    const int jb32 = jbase / BJ;
    const int ntiles = (n >> 2) / BJ;            // 64
    const int iseval = *iseval_p;
    const int jt = wave & 1, kh = wave >> 1;     // QK roles
    const int dq = wave;                         // PV d-quarter
    const int sq = t >> 2, sh = t & 3;           // softmax roles

    if (t < BQ) { MS[t] = -1e30f; LS[t] = 0.f; }

    // ---- Q fragments fp16 (A-layout): this wave's K-half only ----
    half8 Qf[4][4];
    #pragma unroll
    for (int qi = 0; qi < 4; ++qi) {
        const float* np = Ng + (size_t)(q0 + qi * 16 + mn) * EMBED;
        #pragma unroll
        for (int kk = 0; kk < 4; ++kk) {
            const float* p = np + (kh * 4 + kk) * 32 + quad * 8;
            float4 a = *(const float4*)p, b = *(const float4*)(p + 4);
            half8 h;
            h[0]=(_Float16)a.x; h[1]=(_Float16)a.y; h[2]=(_Float16)a.z; h[3]=(_Float16)a.w;
            h[4]=(_Float16)b.x; h[5]=(_Float16)b.y; h[6]=(_Float16)b.z; h[7]=(_Float16)b.w;
            Qf[qi][kk] = h;
        }
    }

    f32x4 O[4][4];
    #pragma unroll
    for (int qi = 0; qi < 4; ++qi)
        #pragma unroll
        for (int dt = 0; dt < 4; ++dt) O[qi][dt] = (f32x4){0.f, 0.f, 0.f, 0.f};

    // QK B base: row j = jbase + tile*BJ + jt*16 + mn, cols kh*128 + kk*32 + quad*8
    const short* mhb0 = MhG + (size_t)(jbase + jt * 16 + mn) * EMBED + kh * 128 + quad * 8;
    half8 Bc[4], Bn[4], Mtf[4];
    #pragma unroll
    for (int kk = 0; kk < 4; ++kk) Bc[kk] = *(const half8*)(mhb0 + kk * 32);

    // Pipelined loop: iter tt does QK(tt) || softmax(tt-1), barrier, PV(tt-1).
    for (int tt = 0; tt <= ntiles; ++tt) {
        const int bw = tt & 1;        // SS buffer written by QK(tt)
        const int br = bw ^ 1;        // buffer of tile tt-1 (valid for tt>0)

        // --- Mt prefetch for PV(tt-1): consumed after the barrier ---
        if (tt > 0) {
            const short* mtb = MtG + (size_t)(jb32 + (tt - 1)) * (BJ * EMBED);
            #pragma unroll
            for (int dt = 0; dt < 4; ++dt)
                Mtf[dt] = *(const half8*)(mtb + (dq * 64 + dt * 16 + mn) * BJ + quad * 8);
        }

        // --- QK^T(tt): 4 q-tiles x this wave's (jt, K-half) -> SS[bw] ---
        if (tt < ntiles) {
            f32x4 a0 = (f32x4){0,0,0,0}, a1 = (f32x4){0,0,0,0};
            f32x4 a2 = (f32x4){0,0,0,0}, a3 = (f32x4){0,0,0,0};
            #pragma unroll
            for (int kk = 0; kk < 4; ++kk) {
                half8 bf = Bc[kk];
                a0 = mfma16(Qf[0][kk], bf, a0);
                a1 = mfma16(Qf[1][kk], bf, a1);
                a2 = mfma16(Qf[2][kk], bf, a2);
                a3 = mfma16(Qf[3][kk], bf, a3);
            }
            float* ssp = (float*)(smem + SS_OFF + bw * SS_BUF) + kh * 2304;
            #pragma unroll
            for (int r = 0; r < 4; ++r) {
                ssp[(0  + quad * 4 + r) * 36 + jt * 16 + mn] = a0[r];
                ssp[(16 + quad * 4 + r) * 36 + jt * 16 + mn] = a1[r];
                ssp[(32 + quad * 4 + r) * 36 + jt * 16 + mn] = a2[r];
                ssp[(48 + quad * 4 + r) * 36 + jt * 16 + mn] = a3[r];
            }
        }

        // --- B-fragment prefetch for QK(tt+1) ---
        if (tt + 1 < ntiles) {
            const short* nb = mhb0 + (size_t)(tt + 1) * (BJ * EMBED);
            #pragma unroll
            for (int kk = 0; kk < 4; ++kk) Bn[kk] = *(const half8*)(nb + kk * 32);
        }

        // --- online softmax(tt-1): thread (sq, sh) owns j = 8sh..8sh+7 ---
        if (tt > 0) {
            const int j0g = jbase + (tt - 1) * BJ;
            const float* p0 = (const float*)(smem + SS_OFF + br * SS_BUF) + sq * 36 + 8 * sh;
            float4 sa = *(const float4*)p0;
            float4 sb = *(const float4*)(p0 + 4);
            float4 sc = *(const float4*)(p0 + 2304);
            float4 sd = *(const float4*)(p0 + 2308);
            float sv[8] = {sa.x + sc.x, sa.y + sc.y, sa.z + sc.z, sa.w + sc.w,
                           sb.x + sd.x, sb.y + sd.y, sb.z + sd.z, sb.w + sd.w};
            const int qg = q0 + sq;
            if (iseval) {
                if (qg == 0) {
                    #pragma unroll
                    for (int i = 0; i < 8; ++i) sv[i] = 0.f;
                }
            } else {
                int dj = qg - j0g - 8 * sh;
                #pragma unroll
                for (int i = 0; i < 8; ++i) if (dj == i) sv[i] = 0.f;
            }
            float mx = sv[0];
            #pragma unroll
            for (int i = 1; i < 8; ++i) mx = fmaxf(mx, sv[i]);
            mx = fmaxf(mx, __shfl_xor(mx, 1));
            mx = fmaxf(mx, __shfl_xor(mx, 2));
            float m_old = MS[sq];
            float m_new = fmaxf(m_old, mx);
            float alpha = __expf(m_old - m_new);
            float p[8], ps = 0.f;
            #pragma unroll
            for (int i = 0; i < 8; ++i) { p[i] = __expf(sv[i] - m_new); ps += p[i]; }
            ps += __shfl_xor(ps, 1);
            ps += __shfl_xor(ps, 2);
            if (sh == 0) {
                MS[sq] = m_new;
                ((float*)(smem + AS_OFF + br * AS_BUF))[sq] = alpha;
                LS[sq] = LS[sq] * alpha + ps;
            }
            half8 ph;
            #pragma unroll
            for (int i = 0; i < 8; ++i) ph[i] = (_Float16)p[i];
            *(half8*)(smem + PH_OFF + br * PH_BUF + sq * 80 + sh * 16) = ph;
        }

        __syncthreads();   // SS[bw] (for next softmax) + PH/AS[br] (for PV) visible

        // --- PV(tt-1): 4 q-tiles x this wave's 4 d-tiles, K=32 ---
        if (tt > 0) {
            #pragma unroll
            for (int qi = 0; qi < 4; ++qi) {
                half8 pf = *(const half8*)(smem + PH_OFF + br * PH_BUF + (qi * 16 + mn) * 80 + quad * 16);
                f32x4 al = *(const f32x4*)((const float*)(smem + AS_OFF + br * AS_BUF) + qi * 16 + quad * 4);
                #pragma unroll
                for (int dt = 0; dt < 4; ++dt) {
                    f32x4 o = O[qi][dt];
                    o[0] *= al[0]; o[1] *= al[1]; o[2] *= al[2]; o[3] *= al[3];
                    O[qi][dt] = mfma16(pf, Mtf[dt], o);
                }
            }
        }

        #pragma unroll
        for (int kk = 0; kk < 4; ++kk) Bc[kk] = Bn[kk];
        // SS[bw] rewrite next happens at QK(tt+2), after barrier(tt+1) which
        // follows softmax(tt+1)'s read? No: softmax(tt+1) reads SS[bw] in iter
        // tt+2... SS[bw] is read by softmax(tt) in iter tt+1 BEFORE barrier(tt+1);
        // QK(tt+2) rewrites it in iter tt+2, after barrier(tt+1). Safe.
        // PH/AS[br] rewrite at softmax(tt+1) in iter tt+2, after barrier(tt+1)
        // which follows PV(tt-1). Safe.
    }

    // ---- epilogue: partial O + (m,l) per split ----
    if (s == 0) {
        #pragma unroll
        for (int qi = 0; qi < 4; ++qi)
            #pragma unroll
            for (int dt = 0; dt < 4; ++dt) {
                int col = dq * 64 + dt * 16 + mn;
                #pragma unroll
                for (int r = 0; r < 4; ++r)
                    O0out[(size_t)(q0 + qi * 16 + quad * 4 + r) * EMBED + col] = O[qi][dt][r];
            }
    } else {
        short* dst = Ofp + (size_t)(s - 1) * n * EMBED;
        #pragma unroll
        for (int qi = 0; qi < 4; ++qi)
            #pragma unroll
            for (int dt = 0; dt < 4; ++dt) {
                int col = dq * 64 + dt * 16 + mn;
                #pragma unroll
                for (int r = 0; r < 4; ++r)
                    dst[(size_t)(q0 + qi * 16 + quad * 4 + r) * EMBED + col] = f2h(O[qi][dt][r]);
            }
    }
    if (t < BQ) {
        MLm[s * n + q0 + t] = MS[t];
        MLl[s * n + q0 + t] = LS[t];
    }
}

// ---------- combine 4 partials + gate + blend ----------
__global__ void combine4(const float* __restrict__ O0, const short* __restrict__ Ofp,
                         const float* __restrict__ MLm, const float* __restrict__ MLl,
                         const float* __restrict__ Ng, const float* __restrict__ Wg,
                         const float* __restrict__ bg, const float* __restrict__ gb,
                         float* __restrict__ out, int n)
{
    const int t = threadIdx.x;
    const int row = blockIdx.x * 16 + (t >> 4);
    const int c = t & 15;
    float ms[4], ls[4];
    #pragma unroll
    for (int k = 0; k < 4; ++k) { ms[k] = MLm[k * n + row]; ls[k] = MLl[k * n + row]; }
    float m = fmaxf(fmaxf(ms[0], ms[1]), fmaxf(ms[2], ms[3]));
    float w[4], lsum = 0.f;
    #pragma unroll
    for (int k = 0; k < 4; ++k) { w[k] = __expf(ms[k] - m); lsum += w[k] * ls[k]; }
    float linv = 1.f / lsum;

    float acc[16];
    {
        const float4* o0 = (const float4*)(O0 + (size_t)row * EMBED + c * 16);
        #pragma unroll
        for (int i = 0; i < 4; ++i) {
            float4 v = o0[i];
            acc[4*i+0] = w[0] * v.x; acc[4*i+1] = w[0] * v.y;
            acc[4*i+2] = w[0] * v.z; acc[4*i+3] = w[0] * v.w;
        }
    }
    #pragma unroll
    for (int k = 1; k < 4; ++k) {
        const short* op = Ofp + (size_t)(k - 1) * n * EMBED + (size_t)row * EMBED + c * 16;
        half8 a = *(const half8*)op, b = *(const half8*)(op + 8);
        #pragma unroll
        for (int i = 0; i < 8; ++i) {
            acc[i]     += w[k] * (float)a[i];
            acc[8 + i] += w[k] * (float)b[i];
        }
    }
    float dot = 0.f;
    #pragma unroll
    for (int i = 0; i < 16; ++i) { acc[i] *= linv; dot += acc[i] * Wg[c * 16 + i]; }
    dot += __shfl_xor(dot, 1);
    dot += __shfl_xor(dot, 2);
    dot += __shfl_xor(dot, 4);
    dot += __shfl_xor(dot, 8);
    float g = 1.f / (1.f + __expf(-(dot + bg[0] + gb[0])));
    const float4* n4 = (const float4*)(Ng + (size_t)row * EMBED + c * 16);
    float4* o4 = (float4*)(out + (size_t)row * EMBED + c * 16);
    #pragma unroll
    for (int i = 0; i < 4; ++i) {
        float4 nn = n4[i];
        float4 res;
        res.x = acc[4*i+0] * g + nn.x * (1.f - g);
        res.y = acc[4*i+1] * g + nn.y * (1.f - g);
        res.z = acc[4*i+2] * g + nn.z * (1.f - g);
        res.w = acc[4*i+3] * g + nn.w * (1.f - g);
        o4[i] = res;
    }
}

extern "C" void kernel_launch(void* const* d_in, const int* in_sizes, int n_in,
                              void* d_out, int out_size, void* d_ws, size_t ws_size,
                              hipStream_t stream) {
    const float* M      = (const float*)d_in[0];
    const float* N      = (const float*)d_in[1];
    const float* Wgp    = (const float*)d_in[2];
    const float* bgp    = (const float*)d_in[3];
    const float* gbp    = (const float*)d_in[4];
    const int*   iseval = (const int*)d_in[5];
    float* out = (float*)d_out;

    int n = in_sizes[0] / EMBED;   // 8192
    short* MhG = (short*)d_ws;                          // n*256 fp16 = 4 MB
    short* MtG = MhG + (size_t)n * EMBED;               // n*256 fp16 = 4 MB
    short* Ofp = MtG + (size_t)n * EMBED;               // 3*n*256 fp16 = 12 MB
    float* MLm = (float*)(Ofp + (size_t)3 * n * EMBED); // 4n f32
    float* MLl = MLm + 4 * n;                           // 4n f32
    // ws required ~20.3 MB

    hipLaunchKernelGGL(prep, dim3(n / 16), dim3(NT), 0, stream, M, MhG, MtG);
    hipLaunchKernelGGL(attn, dim3((n / BQ) * 4), dim3(NT), 0, stream,
                       MhG, MtG, N, iseval, out, Ofp, MLm, MLl, n);
    hipLaunchKernelGGL(combine4, dim3(n / 16), dim3(NT), 0, stream,
                       out, Ofp, MLm, MLl, N, Wgp, bgp, gbp, out, n);
}